// Round 8
// baseline (215.393 us; speedup 1.0000x reference)
//
#include <hip/hip_runtime.h>
#include <hip/hip_bf16.h>
#include <stdint.h>

// C = (B,16,16): diag (k,k)=sigmoid(x·Wd[k]+bd[k]); off (i,j)=-softplus(x·Wo[r]+bo[r])
// Permuted GEMM out[b][c], c=i*16+j. M=65536 N=256 K=1024, bf16 MFMA 16x16x32.
// R8: NO barriers, NO LDS, NO shared state in the main loop. 1024 blocks x 256 thr
// (4 waves). Wave = 64 rows x 64 cols. A-frags straight from global x (reg pack
// fp32->bf16); B-frags straight from fragment-ordered L2 image (4-seg coalesced,
// wave reads only its own 64-col slice). Only true register deps; unroll-2 lets
// the compiler pipeline next-chunk loads under current MFMA. Epilogue: LDS
// transpose (one barrier pair per 16-row band) -> contiguous row stores.

typedef __bf16 bf16x8 __attribute__((ext_vector_type(8)));
typedef float f32x4 __attribute__((ext_vector_type(4)));

#define THREADS 256
#define BM 64
#define NCHUNK 16                  // K chunks of 64
#define CIMG 32768                 // per-chunk image: 2(ks) x 4(q) x 256 c x 16B
#define WBYTES (CIMG * NCHUNK)     // 512 KiB

__device__ __forceinline__ unsigned bf_rtne(unsigned u) {
  return (u + 0x7fffu + ((u >> 16) & 1u)) >> 16;
}
__device__ __forceinline__ unsigned pack2(float lo, float hi) {
  return bf_rtne(__float_as_uint(lo)) | (bf_rtne(__float_as_uint(hi)) << 16);
}
__device__ __forceinline__ bf16x8 packfrag(const float4& a, const float4& b) {
  uint4 u;
  u.x = pack2(a.x, a.y); u.y = pack2(a.z, a.w);
  u.z = pack2(b.x, b.y); u.w = pack2(b.z, b.w);
  return *reinterpret_cast<bf16x8*>(&u);
}

// Fragment-ordered W image (same mapping R2 verified):
// element (c,k): ch=k>>6, ks=(k>>5)&1, q=(k>>3)&3, e=k&7
// byte = ch*CIMG + ks*16384 + q*4096 + c*16 + e*2
// A wave's B-frag load: lane q*16+l15 reads col wn*64+n*16+l15 -> uint4 at
// q*4096 + c*16: 4 contiguous 256B segments per inst.
__global__ void prep_kernel(const float* __restrict__ Wd, const float* __restrict__ bd,
                            const float* __restrict__ Wo, const float* __restrict__ bo,
                            char* __restrict__ wbuf, float* __restrict__ bias) {
  const int c = blockIdx.x;    // 0..255 output col
  const int t = threadIdx.x;   // 0..255, 4 consecutive k each
  const int i = c >> 4, j = c & 15;
  const float* src;
  float b;
  if (i == j) { src = Wd + i * 1024; b = bd[i]; }
  else { int r = i * 15 + (j < i ? j : j - 1); src = Wo + r * 1024; b = bo[r]; }
  if (t == 0) bias[c] = b;
  const int kk = t * 4;
  const int ch = kk >> 6, ks = (kk >> 5) & 1, q = (kk >> 3) & 3, e = kk & 7;
  float4 v = *reinterpret_cast<const float4*>(src + kk);
  uint2 h;
  h.x = pack2(v.x, v.y);
  h.y = pack2(v.z, v.w);
  *reinterpret_cast<uint2*>(wbuf + ch * CIMG + ks * 16384 + q * 4096 + c * 16 + e * 2) = h;
}

__global__ __launch_bounds__(THREADS, 2) void cap_main(
    const float* __restrict__ x, const char* __restrict__ wbuf,
    const float* __restrict__ bias, float* __restrict__ out) {
  __shared__ char smem[16640];  // epilogue only: 16 rows x 1040B

  const int tid = threadIdx.x;
  const int wid = tid >> 6;    // wn: col group 0..3
  const int lane = tid & 63;
  const int l15 = lane & 15;
  const int l4 = lane >> 4;

  const size_t blkRow = (size_t)blockIdx.x * BM;

  // A source: lane (l4,l15) reads row blkRow + m*16 + l15, k = ch*64 + ks*32 + l4*8
  const float* xb = x + (blkRow + (size_t)l15) * 1024 + l4 * 8;
  // B source: lane (l4,l15) reads col wid*64 + n*16 + l15, quarter q=l4
  const char* wb = wbuf + l4 * 4096 + (wid * 64 + l15) * 16;

  f32x4 acc[4][4];
#pragma unroll
  for (int m = 0; m < 4; ++m)
#pragma unroll
    for (int n = 0; n < 4; ++n) acc[m][n] = (f32x4){0.f, 0.f, 0.f, 0.f};

#pragma unroll 2
  for (int ch = 0; ch < NCHUNK; ++ch) {
    // issue all loads for this chunk (no deps on MFMA; compiler pipelines across
    // unrolled iterations -- no barriers anywhere to stop it)
    uint4 bu[2][4];
#pragma unroll
    for (int ks = 0; ks < 2; ++ks)
#pragma unroll
      for (int n = 0; n < 4; ++n)
        bu[ks][n] = *reinterpret_cast<const uint4*>(
            wb + ch * CIMG + ks * 16384 + n * 256);

    float4 ax[4][2][2];
#pragma unroll
    for (int m = 0; m < 4; ++m)
#pragma unroll
      for (int ks = 0; ks < 2; ++ks) {
        const float* p = xb + (size_t)m * 16384 + ch * 64 + ks * 32;
        ax[m][ks][0] = *reinterpret_cast<const float4*>(p);
        ax[m][ks][1] = *reinterpret_cast<const float4*>(p + 4);
      }

    // pack + MFMA
#pragma unroll
    for (int ks = 0; ks < 2; ++ks)
#pragma unroll
      for (int m = 0; m < 4; ++m) {
        bf16x8 af = packfrag(ax[m][ks][0], ax[m][ks][1]);
#pragma unroll
        for (int n = 0; n < 4; ++n)
          acc[m][n] = __builtin_amdgcn_mfma_f32_16x16x32_bf16(
              af, *reinterpret_cast<const bf16x8*>(&bu[ks][n]), acc[m][n], 0, 0, 0);
      }
  }

  // ---- epilogue: bias + activation -> LDS transpose -> contiguous row stores ----
  float bv[4];
#pragma unroll
  for (int n = 0; n < 4; ++n) bv[n] = bias[wid * 64 + n * 16 + l15];

  const int rr = tid >> 4;        // 0..15 read-back row in band
  const int cg = tid & 15;        // 16-float col group
  const char* rdp = smem + rr * 1040 + cg * 64;

  __syncthreads();

#pragma unroll
  for (int p = 0; p < 4; ++p) {   // row band p*16..+16 (acc m-frag p)
#pragma unroll
    for (int n = 0; n < 4; ++n) {
      const int col = wid * 64 + n * 16 + l15;
      const bool diag = (col % 17) == 0;
#pragma unroll
      for (int j2 = 0; j2 < 4; ++j2) {
        float v = acc[p][n][j2] + bv[n];
        float e = __expf(-fabsf(v));
        float sig = (v >= 0.f) ? 1.f / (1.f + e) : e / (1.f + e);
        float sp = fmaxf(v, 0.f) + __logf(1.f + e);
        *reinterpret_cast<float*>(smem + (l4 * 4 + j2) * 1040 + col * 4) =
            diag ? sig : -sp;
      }
    }
    __syncthreads();
    float4 o0 = *reinterpret_cast<const float4*>(rdp);
    float4 o1 = *reinterpret_cast<const float4*>(rdp + 16);
    float4 o2 = *reinterpret_cast<const float4*>(rdp + 32);
    float4 o3 = *reinterpret_cast<const float4*>(rdp + 48);
    float* orow = out + (blkRow + (size_t)(p * 16 + rr)) * 256 + cg * 16;
    *reinterpret_cast<float4*>(orow) = o0;
    *reinterpret_cast<float4*>(orow + 4) = o1;
    *reinterpret_cast<float4*>(orow + 8) = o2;
    *reinterpret_cast<float4*>(orow + 12) = o3;
    __syncthreads();
  }
}

extern "C" void kernel_launch(void* const* d_in, const int* in_sizes, int n_in,
                              void* d_out, int out_size, void* d_ws, size_t ws_size,
                              hipStream_t stream) {
  const float* x = (const float*)d_in[0];
  const float* Wd = (const float*)d_in[1];
  const float* bd = (const float*)d_in[2];
  const float* Wo = (const float*)d_in[3];
  const float* bo = (const float*)d_in[4];
  float* out = (float*)d_out;
  char* wbuf = (char*)d_ws;                  // 512 KiB weight image
  float* bias = (float*)(wbuf + WBYTES);     // 1 KiB bias

  prep_kernel<<<dim3(256), dim3(256), 0, stream>>>(Wd, bd, Wo, bo, wbuf, bias);
  cap_main<<<dim3(1024), dim3(THREADS), 0, stream>>>(x, wbuf, bias, out);
}